// Round 1
// 426.308 us; speedup vs baseline: 1.0071x; 1.0071x over previous
//
#include <hip/hip_runtime.h>
#include <stdint.h>

#define H 4096
#define KSEL 410
#define NT 256
#define FAST_MAX 64u

typedef uint32_t u32x4 __attribute__((ext_vector_type(4)));

__device__ __forceinline__ uint32_t absbits(float f) {
  return __float_as_uint(f) & 0x7fffffffu;
}

// One MSB-first radix-select round over WIDTH bits at SHIFT.
// On entry: target (K-th largest) is the k-th largest among elements whose
// bits above (SHIFT+WIDTH) equal `prefix`. On exit prefix/k are refined.
// CLEAR: clear hist here (else caller pre-cleared). UNCOND: skip prefix test
// (round 1: bits above are always 0 for abs-bit patterns).
template <int SHIFT, int WIDTH, int LOG_PER, bool CLEAR, bool UNCOND>
__device__ __forceinline__ void select_round(
    const uint32_t* __restrict__ u,  // 16 abs-bit values per thread
    uint32_t* hist, uint32_t* aux,
    uint32_t* s_bin, uint32_t* s_k, uint32_t* s_cnt,
    uint32_t& prefix, uint32_t& k, const int tid) {
  constexpr int NB = 1 << WIDTH;
  constexpr int PER = NB / NT;
  static_assert(PER == (1 << LOG_PER), "per mismatch");
  constexpr int HI = SHIFT + WIDTH;                  // bits above this field
  constexpr int PSIZE = NB + (NB >> LOG_PER);        // padded layout size

  if (CLEAR) {
    for (int b = tid; b < PSIZE; b += NT) hist[b] = 0;
    __syncthreads();
  }

  #pragma unroll
  for (int j = 0; j < 16; ++j) {
    const uint32_t uj = u[j];
    if (UNCOND || (uj >> HI) == prefix) {
      const uint32_t b = (uj >> SHIFT) & (NB - 1);
      atomicAdd(&hist[b + (b >> LOG_PER)], 1u);      // padded: conflict-spread
    }
  }
  __syncthreads();

  // local suffix sums over my PER contiguous bins (stride PER+1 -> no bank conflicts)
  uint32_t loc[PER];
  {
    uint32_t sum = 0;
    #pragma unroll
    for (int j = PER - 1; j >= 0; --j) {
      sum += hist[tid * (PER + 1) + j];
      loc[j] = sum;
    }
    aux[tid] = sum;
  }
  __syncthreads();

  // wave 0: replace aux[t] with sum over all t' > t (suffix-exclusive)
  if (tid < 64) {
    uint4 a = ((const uint4*)aux)[tid];
    const uint32_t lsum = a.x + a.y + a.z + a.w;
    uint32_t s = lsum;
    #pragma unroll
    for (int off = 1; off < 64; off <<= 1) {
      uint32_t t = __shfl_down(s, off, 64);
      if (tid + off < 64) s += t;
    }
    const uint32_t above = s - lsum;                 // strictly-above lanes
    uint4 o;
    o.x = above + a.y + a.z + a.w;
    o.y = above + a.z + a.w;
    o.z = above + a.w;
    o.w = above;
    ((uint4*)aux)[tid] = o;
  }
  __syncthreads();

  // find the bin whose suffix range crosses rank k (exactly one thread hits)
  {
    const uint32_t above_t = aux[tid];
    #pragma unroll
    for (int j = 0; j < PER; ++j) {
      const uint32_t s_incl = above_t + loc[j];
      const uint32_t s_abv = (j + 1 < PER) ? (above_t + loc[j + 1]) : above_t;
      if (s_incl >= k && s_abv < k) {
        *s_bin = (uint32_t)(tid * PER + j);
        *s_k = k - s_abv;
        *s_cnt = s_incl - s_abv;                     // size of selected class
      }
    }
  }
  __syncthreads();
  prefix = (prefix << WIDTH) | *s_bin;
  k = *s_k;
}

__global__ __launch_bounds__(NT) void topk_select_kernel(
    const float* __restrict__ x, float* __restrict__ out) {
  __shared__ uint32_t hist1[2304];  // round 1: 2048 bins, padded
  __shared__ uint32_t hist2[1280];  // round 2 (and fallback round 3): 1024 bins, padded
  __shared__ uint32_t aux[NT];
  __shared__ uint32_t s_bin, s_k, s_cnt, s_num, s_tb;

  const int tid = threadIdx.x;
  const size_t base = (size_t)blockIdx.x * H;
  const u32x4* __restrict__ xr = (const u32x4*)(x + base);

  // coalesced streaming load: thread t owns vec4s {t, t+256, t+512, t+768}
  u32x4 r[4];
  #pragma unroll
  for (int j = 0; j < 4; ++j) r[j] = __builtin_nontemporal_load(&xr[tid + j * NT]);

  uint32_t u[16];
  #pragma unroll
  for (int j = 0; j < 4; ++j) {
    #pragma unroll
    for (int c = 0; c < 4; ++c) u[4 * j + c] = r[j][c] & 0x7fffffffu;
  }

  // combined clear for both rounds' histograms (one barrier, overlaps load latency)
  for (int b = tid; b < 2304; b += NT) hist1[b] = 0;
  for (int b = tid; b < 1280; b += NT) hist2[b] = 0;
  if (tid == 0) s_num = 0;
  __syncthreads();

  uint32_t prefix = 0, k = KSEL;
  select_round<20, 11, 3, false, true >(u, hist1, aux, &s_bin, &s_k, &s_cnt, prefix, k, tid);
  select_round<10, 10, 2, false, false>(u, hist2, aux, &s_bin, &s_k, &s_cnt, prefix, k, tid);

  uint32_t tbits, keep_eq, cnt_eq;
  const uint32_t cnt2 = s_cnt;       // class size after 21 bits (uniform)

  if (cnt2 <= FAST_MAX) {
    // FAST PATH (hit ~always for continuous data): exact rank among <=64
    // candidates with one wave; no hist clear, no scan, 2 barriers total.
    // Appends may start immediately: they touch only hist1 (dead) and s_num
    // (untouched since the pre-clear); s_k/s_cnt rewrites happen after the
    // barrier below, protecting the just-completed reads in select_round.
    #pragma unroll
    for (int j = 0; j < 16; ++j) {
      if ((u[j] >> 10) == prefix) {
        const uint32_t p = atomicAdd(&s_num, 1u);
        hist1[p] = u[j];               // reuse dead hist1 as candidate list
      }
    }
    __syncthreads();
    const uint32_t n = s_num;          // == cnt2
    if (tid < 64) {
      const uint32_t myv = (tid < n) ? hist1[tid] : 0u;
      uint32_t g = 0, e = 0;
      for (uint32_t i = 0; i < n; ++i) {   // n ~ 1-2 expected; LDS broadcast
        const uint32_t c = hist1[i];
        g += (c > myv) ? 1u : 0u;
        e += (c == myv) ? 1u : 0u;
      }
      // target class: g < k <= g+e (equal-valued lanes write identical data)
      if (tid < n && g < k && k <= g + e) {
        s_tb = myv;
        s_k = k - g;
        s_cnt = e;
      }
    }
    __syncthreads();
    tbits = s_tb; keep_eq = s_k; cnt_eq = s_cnt;
  } else {
    // rare: huge tie class at 21 bits -> full third radix round (clears hist2)
    select_round<0, 10, 2, true, false>(u, hist2, aux, &s_bin, &s_k, &s_cnt, prefix, k, tid);
    tbits = prefix; keep_eq = k; cnt_eq = s_cnt;
  }

  uint32_t cut = H;                  // default: keep every equal element
  if (cnt_eq != keep_eq) {
    // rare exact tie at the boundary: find index of the keep_eq-th equal
    __syncthreads();                 // drain prior s_* readers
    if (tid == 0) {
      const float* xs = x + base;
      uint32_t c = 0, ct = H;
      for (int i = 0; i < H; ++i) {
        if (absbits(xs[i]) == tbits) {
          if (++c == keep_eq) { ct = (uint32_t)i; break; }
        }
      }
      s_bin = ct;
    }
    __syncthreads();
    cut = s_bin;
  }

  u32x4* __restrict__ outr = (u32x4*)(out + base);
  #pragma unroll
  for (int j = 0; j < 4; ++j) {
    const uint32_t i0 = 4u * (uint32_t)(tid + j * NT);
    u32x4 o;
    #pragma unroll
    for (int c = 0; c < 4; ++c) {
      const uint32_t ub = u[4 * j + c];
      const bool keep = (ub > tbits) || (ub == tbits && (i0 + (uint32_t)c) <= cut);
      o[c] = keep ? r[j][c] : 0u;    // zero float == zero bits
    }
    __builtin_nontemporal_store(o, &outr[tid + j * NT]);
  }
}

extern "C" void kernel_launch(void* const* d_in, const int* in_sizes, int n_in,
                              void* d_out, int out_size, void* d_ws, size_t ws_size,
                              hipStream_t stream) {
  const float* x = (const float*)d_in[0];
  float* out = (float*)d_out;
  const int rows = in_sizes[0] / H;   // 16384
  hipLaunchKernelGGL(topk_select_kernel, dim3(rows), dim3(NT), 0, stream, x, out);
}

// Round 2
// 416.575 us; speedup vs baseline: 1.0307x; 1.0234x over previous
//
#include <hip/hip_runtime.h>
#include <stdint.h>

#define H 4096
#define KSEL 410
#define NT 256
#define FAST_MAX 256u

typedef uint32_t u32x4 __attribute__((ext_vector_type(4)));

__device__ __forceinline__ uint32_t absbits(float f) {
  return __float_as_uint(f) & 0x7fffffffu;
}

// One MSB-first radix-select round over WIDTH bits at SHIFT, reading abs-bits
// on the fly from the register-held row data r[4] (16 values per thread).
// On entry: target (K-th largest) is the k-th largest among elements whose
// bits above (SHIFT+WIDTH) equal `prefix`. On exit prefix/k are refined.
template <int SHIFT, int WIDTH, int LOG_PER, bool CLEAR, bool UNCOND>
__device__ __forceinline__ void select_round(
    const u32x4* __restrict__ r,
    uint32_t* hist, uint32_t* aux,
    uint32_t* s_bin, uint32_t* s_k, uint32_t* s_cnt,
    uint32_t& prefix, uint32_t& k, const int tid) {
  constexpr int NB = 1 << WIDTH;
  constexpr int PER = NB / NT;
  static_assert(PER == (1 << LOG_PER), "per mismatch");
  constexpr int HI = SHIFT + WIDTH;                  // bits above this field
  constexpr int PSIZE = NB + (NB >> LOG_PER);        // padded layout size

  if (CLEAR) {
    for (int b = tid; b < PSIZE; b += NT) hist[b] = 0;
    __syncthreads();
  }

  #pragma unroll
  for (int jv = 0; jv < 4; ++jv) {
    #pragma unroll
    for (int c = 0; c < 4; ++c) {
      const uint32_t uj = r[jv][c] & 0x7fffffffu;
      if (UNCOND || (uj >> HI) == prefix) {
        const uint32_t b = (uj >> SHIFT) & (NB - 1);
        atomicAdd(&hist[b + (b >> LOG_PER)], 1u);    // padded: conflict-spread
      }
    }
  }
  __syncthreads();

  // local suffix sums over my PER contiguous bins (stride PER+1 -> no bank conflicts)
  uint32_t loc[PER];
  {
    uint32_t sum = 0;
    #pragma unroll
    for (int j = PER - 1; j >= 0; --j) {
      sum += hist[tid * (PER + 1) + j];
      loc[j] = sum;
    }
    aux[tid] = sum;
  }
  __syncthreads();

  // wave 0: replace aux[t] with sum over all t' > t (suffix-exclusive)
  if (tid < 64) {
    uint4 a = ((const uint4*)aux)[tid];
    const uint32_t lsum = a.x + a.y + a.z + a.w;
    uint32_t s = lsum;
    #pragma unroll
    for (int off = 1; off < 64; off <<= 1) {
      uint32_t t = __shfl_down(s, off, 64);
      if (tid + off < 64) s += t;
    }
    const uint32_t above = s - lsum;                 // strictly-above lanes
    uint4 o;
    o.x = above + a.y + a.z + a.w;
    o.y = above + a.z + a.w;
    o.z = above + a.w;
    o.w = above;
    ((uint4*)aux)[tid] = o;
  }
  __syncthreads();

  // find the bin whose suffix range crosses rank k (exactly one thread hits)
  {
    const uint32_t above_t = aux[tid];
    #pragma unroll
    for (int j = 0; j < PER; ++j) {
      const uint32_t s_incl = above_t + loc[j];
      const uint32_t s_abv = (j + 1 < PER) ? (above_t + loc[j + 1]) : above_t;
      if (s_incl >= k && s_abv < k) {
        *s_bin = (uint32_t)(tid * PER + j);
        *s_k = k - s_abv;
        *s_cnt = s_incl - s_abv;                     // size of selected class
      }
    }
  }
  __syncthreads();
  prefix = (prefix << WIDTH) | *s_bin;
  k = *s_k;
}

__global__ __launch_bounds__(NT) void topk_select_kernel(
    const float* __restrict__ x, float* __restrict__ out) {
  __shared__ uint32_t hist[2304];   // 2048 bins padded (also fallback rounds)
  __shared__ uint32_t cand[256];    // fast-path candidate values
  __shared__ uint32_t aux[NT];
  __shared__ uint32_t s_bin, s_k, s_cnt, s_num, s_tb;

  const int tid = threadIdx.x;
  const size_t base = (size_t)blockIdx.x * H;
  const u32x4* __restrict__ xr = (const u32x4*)(x + base);

  // coalesced streaming load: thread t owns vec4s {t, t+256, t+512, t+768}
  u32x4 r[4];
  #pragma unroll
  for (int j = 0; j < 4; ++j) r[j] = __builtin_nontemporal_load(&xr[tid + j * NT]);

  // clear round-1 histogram + append cursor (one barrier, overlaps load latency)
  for (int b = tid; b < 2304; b += NT) hist[b] = 0;
  if (tid == 0) s_num = 0;
  __syncthreads();

  // Round 1: top 11 bits of abs pattern (bit 31 is always 0 -> unconditional)
  uint32_t prefix = 0, k = KSEL;
  select_round<20, 11, 3, false, true>(r, hist, aux, &s_bin, &s_k, &s_cnt, prefix, k, tid);

  uint32_t tbits, keep_eq, cnt_eq;
  const uint32_t cnt1 = s_cnt;       // class size after 11 bits (uniform)

  if (cnt1 <= FAST_MAX) {
    // FAST PATH (hit ~always for continuous data; E[cnt1] ~ 100): gather the
    // class and rank exactly. Replaces a whole histogram round (clear + 16
    // predicated atomics + 2-level scan + 4 barriers) with gather + O(n^2)
    // LDS-broadcast count. s_num untouched since pre-clear; s_k/s_cnt are
    // rewritten only after the barrier below, protecting select_round's reads.
    #pragma unroll
    for (int jv = 0; jv < 4; ++jv) {
      #pragma unroll
      for (int c = 0; c < 4; ++c) {
        const uint32_t uj = r[jv][c] & 0x7fffffffu;
        if ((uj >> 20) == prefix) cand[atomicAdd(&s_num, 1u)] = uj;
      }
    }
    __syncthreads();
    const uint32_t n = cnt1;
    const uint32_t myv = ((uint32_t)tid < n) ? cand[tid] : 0u;
    uint32_t g = 0, e = 0;
    for (uint32_t i = 0; i < n; ++i) {   // LDS broadcast reads, ~100 iters
      const uint32_t c = cand[i];
      g += (c > myv) ? 1u : 0u;
      e += (c == myv) ? 1u : 0u;
    }
    // target class: g < k <= g+e (equal-valued lanes write identical data)
    if ((uint32_t)tid < n && g < k && k <= g + e) {
      s_tb = myv;
      s_k = k - g;
      s_cnt = e;
    }
    __syncthreads();
    tbits = s_tb; keep_eq = s_k; cnt_eq = s_cnt;
  } else {
    // rare: huge tie class at 11 bits -> two more full radix rounds
    select_round<10, 10, 2, true, false>(r, hist, aux, &s_bin, &s_k, &s_cnt, prefix, k, tid);
    select_round< 0, 10, 2, true, false>(r, hist, aux, &s_bin, &s_k, &s_cnt, prefix, k, tid);
    tbits = prefix; keep_eq = k; cnt_eq = s_cnt;
  }

  uint32_t cut = H;                  // default: keep every equal element
  if (cnt_eq != keep_eq) {
    // rare exact tie at the boundary: find index of the keep_eq-th equal
    __syncthreads();                 // drain prior s_* readers
    if (tid == 0) {
      const float* xs = x + base;
      uint32_t c = 0, ct = H;
      for (int i = 0; i < H; ++i) {
        if (absbits(xs[i]) == tbits) {
          if (++c == keep_eq) { ct = (uint32_t)i; break; }
        }
      }
      s_bin = ct;
    }
    __syncthreads();
    cut = s_bin;
  }

  u32x4* __restrict__ outr = (u32x4*)(out + base);
  #pragma unroll
  for (int j = 0; j < 4; ++j) {
    const uint32_t i0 = 4u * (uint32_t)(tid + j * NT);
    u32x4 o;
    #pragma unroll
    for (int c = 0; c < 4; ++c) {
      const uint32_t ub = r[j][c] & 0x7fffffffu;
      const bool keep = (ub > tbits) || (ub == tbits && (i0 + (uint32_t)c) <= cut);
      o[c] = keep ? r[j][c] : 0u;    // zero float == zero bits
    }
    __builtin_nontemporal_store(o, &outr[tid + j * NT]);
  }
}

extern "C" void kernel_launch(void* const* d_in, const int* in_sizes, int n_in,
                              void* d_out, int out_size, void* d_ws, size_t ws_size,
                              hipStream_t stream) {
  const float* x = (const float*)d_in[0];
  float* out = (float*)d_out;
  const int rows = in_sizes[0] / H;   // 16384
  hipLaunchKernelGGL(topk_select_kernel, dim3(rows), dim3(NT), 0, stream, x, out);
}